// Round 8
// baseline (97.194 us; speedup 1.0000x reference)
//
#include <hip/hip_runtime.h>

// Problem constants (fixed by the reference setup)
#define NV   1024          // number of segments
#define PB   32            // histogram bins per axis
#define BHW  25600         // H*W = 160*160
#define CAP  256           // queue capacity; seg sizes ~ Binomial(102400,1/1024): mean 100, sd 10 -> 15.6 sigma
#define KST  72            // K-stride in shorts (64 + 8 pad): 144 B rows, 16B-aligned, no pow2 bank stride
#define SPB  8             // segments per block (grid = NV/SPB = 128)

typedef short short8   __attribute__((ext_vector_type(8)));
typedef float floatx16 __attribute__((ext_vector_type(16)));

// exp(-0.5*((t-m-0.5)*1.25)^2) == exp2(-(e*e)) with e = 1.0616525*(t-m-0.5)
#define ESC 1.0616525f

// float -> bf16 (round-to-nearest-even); inputs are finite non-negative weights
__device__ __forceinline__ unsigned short f2bf(float f) {
    unsigned u = __builtin_bit_cast(unsigned, f);
    return (unsigned short)((u + 0x7FFFu + ((u >> 16) & 1u)) >> 16);
}

// ONE kernel, one graph node. Block b (256 thr = 4 waves) serves segments
// 8b..8b+7 (grid 128). r7 showed the seg scan is L2 broadcast-congestion
// bound (aggregate bytes = grid x 400 KB; ~6 TB/s effective) — 8 segs/block
// cuts aggregate volume 4x (205 -> 51 MB) at unchanged per-thread work.
//   phase 1: scan seg with 8 int4 loads in flight; matching indices -> 8 LDS
//            queues ((s>>3)==b, queue s&7) via LDS atomics.
//   phase 2: 16 (seg,pair) tasks over 4 waves, 4 sequential tasks per wave.
//            BARRIER-FREE: each wave builds its private LDS A/B bf16 matrices
//            and immediately consumes them with v_mfma_f32_32x32x16_bf16
//            (per-wave DS ops are in-order; wave_barrier stops compiler
//            reordering). Tail lanes use sentinel te=-1e9 -> exp2 -> exact 0.
//   phase 3: per task: scale by 1/cnt, store straight from acc.
__global__ void __launch_bounds__(256, 2)
fused_kernel(const int4* __restrict__ seg4,
             const int* __restrict__ byx1, const int* __restrict__ byx2,
             const float* __restrict__ grad,
             float* __restrict__ out, int N4) {
    __shared__ __align__(16) unsigned short W[4 * 2 * PB * KST];   // 36 KB: per-wave A,B
    __shared__ unsigned q[SPB][CAP];                               // 8 KB
    __shared__ unsigned qc[SPB];

    const int bv   = blockIdx.x;          // serves segments SPB*bv .. SPB*bv+7
    const int tid  = threadIdx.x;
    const int lane = tid & 63;
    const int wv   = tid >> 6;

    if (tid < SPB) qc[tid] = 0u;
    __syncthreads();

    // ---- phase 1: scan + compact, 8 loads in flight ----
#define CHK(f, n) if (((f) >> 3) == bv) { \
        unsigned p = atomicAdd(&qc[(f) & 7], 1u); \
        if (p < CAP) q[(f) & 7][p] = (unsigned)(n); }
#define CHK4(r, i) CHK((r).x, 4*(i)+0) CHK((r).y, 4*(i)+1) CHK((r).z, 4*(i)+2) CHK((r).w, 4*(i)+3)
    int i = tid;
    for (; i + 7 * 256 < N4; i += 8 * 256) {
        int4 r0 = seg4[i + 0 * 256];
        int4 r1 = seg4[i + 1 * 256];
        int4 r2 = seg4[i + 2 * 256];
        int4 r3 = seg4[i + 3 * 256];
        int4 r4 = seg4[i + 4 * 256];
        int4 r5 = seg4[i + 5 * 256];
        int4 r6 = seg4[i + 6 * 256];
        int4 r7 = seg4[i + 7 * 256];
        CHK4(r0, i + 0 * 256) CHK4(r1, i + 1 * 256) CHK4(r2, i + 2 * 256) CHK4(r3, i + 3 * 256)
        CHK4(r4, i + 4 * 256) CHK4(r5, i + 5 * 256) CHK4(r6, i + 6 * 256) CHK4(r7, i + 7 * 256)
    }
    for (; i + 3 * 256 < N4; i += 4 * 256) {
        int4 r0 = seg4[i + 0 * 256];
        int4 r1 = seg4[i + 1 * 256];
        int4 r2 = seg4[i + 2 * 256];
        int4 r3 = seg4[i + 3 * 256];
        CHK4(r0, i + 0 * 256) CHK4(r1, i + 1 * 256) CHK4(r2, i + 2 * 256) CHK4(r3, i + 3 * 256)
    }
    for (; i < N4; i += 256) {
        int4 r0 = seg4[i];
        CHK4(r0, i)
    }
#undef CHK4
#undef CHK
    __syncthreads();

    // ---- phase 2+3: 16 (seg,pair) tasks, 4 per wave, barrier-free ----
    unsigned short* matA = &W[wv * 2 * PB * KST];
    unsigned short* matB = matA + PB * KST;

    for (int t = wv; t < 2 * SPB; t += 4) {
        const int sl = t >> 1;            // local segment 0..7
        const int pr = t & 1;             // 0: coords pair, 1: grad pair
        const unsigned cnt = min(qc[sl], (unsigned)CAP);

        floatx16 acc = {0,0,0,0,0,0,0,0,0,0,0,0,0,0,0,0};

        for (unsigned base = 0; base < cnt; base += 64u) {
            // stage 1: weight columns (scaled bin coords te; sentinel -> 0 weight)
            unsigned idx = base + (unsigned)lane;
            float te0 = -1e9f, te1 = -1e9f;
            if (idx < cnt) {
                unsigned n = q[sl][idx];
                if (pr == 0) {
                    te0 = (float)byx1[n] * (0.2f * ESC);      // ((2*byx/160-1)+1)*16 * ESC
                    te1 = (float)byx2[n] * (0.2f * ESC);
                } else {
                    unsigned b  = n / BHW;
                    unsigned hw = n - b * BHW;
                    te0 = fmaf(grad[(b * 2u + 0u) * BHW + hw], 16.0f * ESC, 16.0f * ESC);
                    te1 = fmaf(grad[(b * 2u + 1u) * BHW + hw], 16.0f * ESC, 16.0f * ESC);
                }
            }
            unsigned short* c0 = matA + lane;                 // column `lane`
            unsigned short* c1 = matB + lane;
#pragma unroll
            for (int mm = 0; mm < PB; ++mm) {
                float cm = ((float)mm + 0.5f) * ESC;          // compile-time const
                float e0 = te0 - cm;
                float e1 = te1 - cm;
                c0[mm * KST] = f2bf(__builtin_amdgcn_exp2f(-(e0 * e0)));
                c1[mm * KST] = f2bf(__builtin_amdgcn_exp2f(-(e1 * e1)));
            }
            __builtin_amdgcn_wave_barrier();   // keep compiler from hoisting reads above writes

            // stage 2: 4 MFMAs consume the K=64 tile (same wave wrote it; DS is in-order)
            const int m = lane & 31;
            const int h = lane >> 5;
            const unsigned short* pa = matA + m * KST + h * 8;
            const unsigned short* pb = matB + m * KST + h * 8;
#pragma unroll
            for (int k = 0; k < 4; ++k) {
                short8 af = *(const short8*)(pa + k * 16);    // ds_read_b128
                short8 bf = *(const short8*)(pb + k * 16);
                acc = __builtin_amdgcn_mfma_f32_32x32x16_bf16(af, bf, acc, 0, 0, 0);
            }
            __builtin_amdgcn_wave_barrier();   // next iter's writes stay after these reads
        }

        // phase 3: scale + store. C/D: col=lane&31, row=(r&3)+8*(r>>2)+4*(lane>>5)
        float inv = (cnt > 0) ? (1.0f / (float)cnt) : 0.0f;   // den = sizes * (P/32)^2 = sizes
        float* o = out + ((size_t)(SPB * bv + sl) * 2 + pr) * (PB * PB);
        const int col = lane & 31;
        const int rb  = (lane >> 5) * 4;
#pragma unroll
        for (int r = 0; r < 16; ++r) {
            int row = (r & 3) + 8 * (r >> 2) + rb;
            o[row * PB + col] = acc[r] * inv;
        }
    }
}

extern "C" void kernel_launch(void* const* d_in, const int* in_sizes, int n_in,
                              void* d_out, int out_size, void* d_ws, size_t ws_size,
                              hipStream_t stream) {
    const int*   seg  = (const int*)d_in[0];
    const int*   byx  = (const int*)d_in[1];
    const float* grad = (const float*)d_in[2];
    float* out = (float*)d_out;

    int N = in_sizes[0];                 // B*H*W = 102400 (multiple of 4)
    const int* byx1 = byx + N;           // row 1 of (3, N)
    const int* byx2 = byx + 2 * N;       // row 2

    fused_kernel<<<NV / SPB, 256, 0, stream>>>((const int4*)seg, byx1, byx2, grad, out, N / 4);
}

// Round 9
// 76.737 us; speedup vs baseline: 1.2666x; 1.2666x over previous
//
#include <hip/hip_runtime.h>

// Problem constants (fixed by the reference setup)
#define NV   1024          // number of segments
#define PB   32            // histogram bins per axis
#define BHW  25600         // H*W = 160*160
#define CAP  256           // queue capacity; seg sizes ~ Binomial(102400,1/1024): mean 100, sd 10 -> 15.6 sigma
#define KST  72            // K-stride in shorts (64 + 8 pad): 144 B rows, 16B-aligned, no pow2 bank stride
#define SPB  8             // segments per block
#define TPB  1024          // threads per block (16 waves: one per (seg,pair) task)

typedef short short8   __attribute__((ext_vector_type(8)));
typedef float floatx16 __attribute__((ext_vector_type(16)));

// exp(-0.5*((t-m-0.5)*1.25)^2) == exp2(-(e*e)) with e = 1.0616525*(t-m-0.5)
#define ESC 1.0616525f

// float -> bf16 (round-to-nearest-even); inputs are finite non-negative weights
__device__ __forceinline__ unsigned short f2bf(float f) {
    unsigned u = __builtin_bit_cast(unsigned, f);
    return (unsigned short)((u + 0x7FFFu + ((u >> 16) & 1u)) >> 16);
}

// ONE kernel, one graph node. Block b (1024 thr = 16 waves) serves segments
// 8b..8b+7 (grid 128). r7/r8 established the seg scan is per-thread-latency
// bound: wall ~ (loads/thread x latency) / (waves/SIMD). 1024-thr blocks cut
// loads/thread 4x (25 int4) AND double waves/SIMD (4) vs r7.
//   phase 1: scan seg with 8 int4 loads in flight; matching indices -> 8 LDS
//            queues ((s>>3)==b, queue s&7) via LDS atomics.
//   phase 2: 16 (seg,pair) tasks <-> 16 waves, exactly 1 task per wave.
//            BARRIER-FREE: each wave builds its private LDS A/B bf16 matrices
//            and immediately consumes them with v_mfma_f32_32x32x16_bf16
//            (per-wave DS ops are in-order; wave_barrier stops compiler
//            reordering). Tail lanes use sentinel te=-1e9 -> exp2 -> exact 0.
//   phase 3: scale by 1/cnt, store straight from acc.
// LDS: 16 waves x 2 matrices x (32*72*2 B) = 147456 B + queues 8 KB = ~152 KB
// (fits the 160 KiB/CU of gfx950; 1 block/CU).
__global__ void __launch_bounds__(TPB, 1)
fused_kernel(const int4* __restrict__ seg4,
             const int* __restrict__ byx1, const int* __restrict__ byx2,
             const float* __restrict__ grad,
             float* __restrict__ out, int N4) {
    __shared__ __align__(16) unsigned short W[16 * 2 * PB * KST];  // 147 KB
    __shared__ unsigned q[SPB][CAP];                               // 8 KB
    __shared__ unsigned qc[SPB];

    const int bv   = blockIdx.x;          // serves segments SPB*bv .. SPB*bv+7
    const int tid  = threadIdx.x;
    const int lane = tid & 63;
    const int wv   = tid >> 6;            // 0..15

    if (tid < SPB) qc[tid] = 0u;
    __syncthreads();

    // ---- phase 1: scan + compact, 8 loads in flight, 25 iters/thread ----
#define CHK(f, n) if (((f) >> 3) == bv) { \
        unsigned p = atomicAdd(&qc[(f) & 7], 1u); \
        if (p < CAP) q[(f) & 7][p] = (unsigned)(n); }
#define CHK4(r, i) CHK((r).x, 4*(i)+0) CHK((r).y, 4*(i)+1) CHK((r).z, 4*(i)+2) CHK((r).w, 4*(i)+3)
    int i = tid;
    for (; i + 7 * TPB < N4; i += 8 * TPB) {
        int4 r0 = seg4[i + 0 * TPB];
        int4 r1 = seg4[i + 1 * TPB];
        int4 r2 = seg4[i + 2 * TPB];
        int4 r3 = seg4[i + 3 * TPB];
        int4 r4 = seg4[i + 4 * TPB];
        int4 r5 = seg4[i + 5 * TPB];
        int4 r6 = seg4[i + 6 * TPB];
        int4 r7 = seg4[i + 7 * TPB];
        CHK4(r0, i + 0 * TPB) CHK4(r1, i + 1 * TPB) CHK4(r2, i + 2 * TPB) CHK4(r3, i + 3 * TPB)
        CHK4(r4, i + 4 * TPB) CHK4(r5, i + 5 * TPB) CHK4(r6, i + 6 * TPB) CHK4(r7, i + 7 * TPB)
    }
    for (; i < N4; i += TPB) {
        int4 r0 = seg4[i];
        CHK4(r0, i)
    }
#undef CHK4
#undef CHK
    __syncthreads();

    // ---- phase 2: one (seg,pair) task per wave, barrier-free MFMA ----
    const int sl = wv >> 1;               // local segment 0..7
    const int pr = wv & 1;                // 0: coords pair, 1: grad pair
    const unsigned cnt = min(qc[sl], (unsigned)CAP);

    unsigned short* matA = &W[wv * 2 * PB * KST];
    unsigned short* matB = matA + PB * KST;

    floatx16 acc = {0,0,0,0,0,0,0,0,0,0,0,0,0,0,0,0};

    for (unsigned base = 0; base < cnt; base += 64u) {
        // stage 1: weight columns (scaled bin coords te; sentinel -> 0 weight)
        unsigned idx = base + (unsigned)lane;
        float te0 = -1e9f, te1 = -1e9f;
        if (idx < cnt) {
            unsigned n = q[sl][idx];
            if (pr == 0) {
                te0 = (float)byx1[n] * (0.2f * ESC);      // ((2*byx/160-1)+1)*16 * ESC
                te1 = (float)byx2[n] * (0.2f * ESC);
            } else {
                unsigned b  = n / BHW;
                unsigned hw = n - b * BHW;
                te0 = fmaf(grad[(b * 2u + 0u) * BHW + hw], 16.0f * ESC, 16.0f * ESC);
                te1 = fmaf(grad[(b * 2u + 1u) * BHW + hw], 16.0f * ESC, 16.0f * ESC);
            }
        }
        unsigned short* c0 = matA + lane;                 // column `lane`, 144 B rows
        unsigned short* c1 = matB + lane;
#pragma unroll
        for (int mm = 0; mm < PB; ++mm) {
            float cm = ((float)mm + 0.5f) * ESC;          // compile-time const
            float e0 = te0 - cm;
            float e1 = te1 - cm;
            c0[mm * KST] = f2bf(__builtin_amdgcn_exp2f(-(e0 * e0)));
            c1[mm * KST] = f2bf(__builtin_amdgcn_exp2f(-(e1 * e1)));
        }
        __builtin_amdgcn_wave_barrier();   // keep compiler from hoisting reads above writes

        // stage 2: 4 MFMAs consume the K=64 tile (same wave wrote it; DS is in-order)
        const int m = lane & 31;
        const int h = lane >> 5;
        const unsigned short* pa = matA + m * KST + h * 8;
        const unsigned short* pb = matB + m * KST + h * 8;
#pragma unroll
        for (int k = 0; k < 4; ++k) {
            short8 af = *(const short8*)(pa + k * 16);    // ds_read_b128
            short8 bf = *(const short8*)(pb + k * 16);
            acc = __builtin_amdgcn_mfma_f32_32x32x16_bf16(af, bf, acc, 0, 0, 0);
        }
        __builtin_amdgcn_wave_barrier();   // next iter's writes stay after these reads
    }

    // ---- phase 3: scale + store. C/D: col=lane&31, row=(r&3)+8*(r>>2)+4*(lane>>5) ----
    float inv = (cnt > 0) ? (1.0f / (float)cnt) : 0.0f;   // den = sizes * (P/32)^2 = sizes
    float* o = out + ((size_t)(SPB * bv + sl) * 2 + pr) * (PB * PB);
    const int col = lane & 31;
    const int rb  = (lane >> 5) * 4;
#pragma unroll
    for (int r = 0; r < 16; ++r) {
        int row = (r & 3) + 8 * (r >> 2) + rb;
        o[row * PB + col] = acc[r] * inv;
    }
}

extern "C" void kernel_launch(void* const* d_in, const int* in_sizes, int n_in,
                              void* d_out, int out_size, void* d_ws, size_t ws_size,
                              hipStream_t stream) {
    const int*   seg  = (const int*)d_in[0];
    const int*   byx  = (const int*)d_in[1];
    const float* grad = (const float*)d_in[2];
    float* out = (float*)d_out;

    int N = in_sizes[0];                 // B*H*W = 102400 (multiple of 4)
    const int* byx1 = byx + N;           // row 1 of (3, N)
    const int* byx2 = byx + 2 * N;       // row 2

    fused_kernel<<<NV / SPB, TPB, 0, stream>>>((const int4*)seg, byx1, byx2, grad, out, N / 4);
}